// Round 5
// baseline (53.178 us; speedup 1.0000x reference)
//
#include <hip/hip_runtime.h>

#define N_NODES  100000
#define N_EDGES  3200000
#define D_FEAT   128
#define SLICE    33344         // 3 slices cover 100000; 130.25 KiB LDS
#define SLICE4   (SLICE / 4)
#define N_SLICES 3
#define MAX_B    85            // 3*85 = 255 blocks, ~1 per CU
#define EPT      8             // edges per thread per pipeline stage
#define TPB      1024
#define STRIDE   (TPB * EPT)   // 8192 edges per stage per block

__device__ __forceinline__ unsigned short f2bf(float f) {
    union { float f; unsigned u; } c; c.f = f;
    unsigned r = c.u + 0x7FFFu + ((c.u >> 16) & 1u);   // round-nearest-even
    return (unsigned short)(r >> 16);
}
__device__ __forceinline__ float bf2f(unsigned short h) {
    union { unsigned u; float f; } c; c.u = ((unsigned)h) << 16; return c.f;
}

// ---------------------------------------------------------------------------
// Kernel 1: per-node feature row-sum. 32 lanes per row, float4 per lane.
// ---------------------------------------------------------------------------
__global__ void __launch_bounds__(256) rowsum_kernel(
    const float* __restrict__ feat,
    float* __restrict__ rowsum)
{
    const int gid = (int)(blockIdx.x * blockDim.x + threadIdx.x);
    const int row = gid >> 5;
    const int sub = gid & 31;
    if (row >= N_NODES) return;

    const float4 v = reinterpret_cast<const float4*>(
        feat + (size_t)row * D_FEAT)[sub];
    float s = (v.x + v.y) + (v.z + v.w);

    #pragma unroll
    for (int off = 16; off > 0; off >>= 1)
        s += __shfl_xor(s, off, 64);

    if (sub == 0) rowsum[row] = s;
}

// ---------------------------------------------------------------------------
// Kernel 2: LDS-privatized scatter with 3-stage software pipeline.
// iter k: issue idx loads(k+2) ; issue gathers(k+1) ; commit ds_add(k).
// Each memory class gets one full iteration of latency hiding.
// Validity is baked into j (invalid -> 0xFFFFFFFF >= len -> no gather/commit).
// ---------------------------------------------------------------------------
__global__ void __launch_bounds__(TPB) scatter_kernel(
    const int* __restrict__ edge_src,
    const int* __restrict__ edge_dst,
    const float* __restrict__ rowsum,
    unsigned short* __restrict__ copies,
    int B, int epb)
{
    __shared__ float lds[SLICE];

    const int tid = (int)threadIdx.x;
    const int b   = (int)blockIdx.x;
    const int s   = (int)blockIdx.y;
    const int lo  = s * SLICE;
    const unsigned len = (unsigned)((N_NODES - lo < SLICE) ? (N_NODES - lo) : SLICE);

    float4 z; z.x = z.y = z.z = z.w = 0.0f;
    for (int i = tid; i < SLICE4; i += TPB)
        reinterpret_cast<float4*>(lds)[i] = z;
    __syncthreads();

    const int begin = b * epb;
    const int end   = (begin + epb < N_EDGES) ? begin + epb : N_EDGES;

    int eA = begin + tid * EPT;   // stage being committed
    int eB = eA + STRIDE;         // stage being gathered

    // ---- prologue: load idx(A), idx(B); gather(A) ----
    int4 dA0, dA1, sA0, sA1, dB0, dB1, sB0, sB1;
    if (eA     < end) { dA0 = *(const int4*)(edge_dst + eA);     sA0 = *(const int4*)(edge_src + eA); }
    if (eA + 4 < end) { dA1 = *(const int4*)(edge_dst + eA + 4); sA1 = *(const int4*)(edge_src + eA + 4); }
    if (eB     < end) { dB0 = *(const int4*)(edge_dst + eB);     sB0 = *(const int4*)(edge_src + eB); }
    if (eB + 4 < end) { dB1 = *(const int4*)(edge_dst + eB + 4); sB1 = *(const int4*)(edge_src + eB + 4); }

    unsigned jA0, jA1, jA2, jA3, jA4, jA5, jA6, jA7;
    float    wA0, wA1, wA2, wA3, wA4, wA5, wA6, wA7;
    {
        const bool v0 = (eA < end), v1 = (eA + 4 < end);
        jA0 = v0 ? (unsigned)(dA0.x - lo) : 0xFFFFFFFFu;
        jA1 = v0 ? (unsigned)(dA0.y - lo) : 0xFFFFFFFFu;
        jA2 = v0 ? (unsigned)(dA0.z - lo) : 0xFFFFFFFFu;
        jA3 = v0 ? (unsigned)(dA0.w - lo) : 0xFFFFFFFFu;
        jA4 = v1 ? (unsigned)(dA1.x - lo) : 0xFFFFFFFFu;
        jA5 = v1 ? (unsigned)(dA1.y - lo) : 0xFFFFFFFFu;
        jA6 = v1 ? (unsigned)(dA1.z - lo) : 0xFFFFFFFFu;
        jA7 = v1 ? (unsigned)(dA1.w - lo) : 0xFFFFFFFFu;
        wA0 = (jA0 < len) ? rowsum[sA0.x] : 0.0f;
        wA1 = (jA1 < len) ? rowsum[sA0.y] : 0.0f;
        wA2 = (jA2 < len) ? rowsum[sA0.z] : 0.0f;
        wA3 = (jA3 < len) ? rowsum[sA0.w] : 0.0f;
        wA4 = (jA4 < len) ? rowsum[sA1.x] : 0.0f;
        wA5 = (jA5 < len) ? rowsum[sA1.y] : 0.0f;
        wA6 = (jA6 < len) ? rowsum[sA1.z] : 0.0f;
        wA7 = (jA7 < len) ? rowsum[sA1.w] : 0.0f;
    }

    while (eA < end) {
        // (1) issue idx loads for stage k+2
        const int eC = eB + STRIDE;
        int4 dC0, dC1, sC0, sC1;
        if (eC     < end) { dC0 = *(const int4*)(edge_dst + eC);     sC0 = *(const int4*)(edge_src + eC); }
        if (eC + 4 < end) { dC1 = *(const int4*)(edge_dst + eC + 4); sC1 = *(const int4*)(edge_src + eC + 4); }

        // (2) issue gathers for stage k+1 (indices arrived one iter ago)
        const bool v0 = (eB < end), v1 = (eB + 4 < end);
        unsigned jB0 = v0 ? (unsigned)(dB0.x - lo) : 0xFFFFFFFFu;
        unsigned jB1 = v0 ? (unsigned)(dB0.y - lo) : 0xFFFFFFFFu;
        unsigned jB2 = v0 ? (unsigned)(dB0.z - lo) : 0xFFFFFFFFu;
        unsigned jB3 = v0 ? (unsigned)(dB0.w - lo) : 0xFFFFFFFFu;
        unsigned jB4 = v1 ? (unsigned)(dB1.x - lo) : 0xFFFFFFFFu;
        unsigned jB5 = v1 ? (unsigned)(dB1.y - lo) : 0xFFFFFFFFu;
        unsigned jB6 = v1 ? (unsigned)(dB1.z - lo) : 0xFFFFFFFFu;
        unsigned jB7 = v1 ? (unsigned)(dB1.w - lo) : 0xFFFFFFFFu;
        float wB0 = (jB0 < len) ? rowsum[sB0.x] : 0.0f;
        float wB1 = (jB1 < len) ? rowsum[sB0.y] : 0.0f;
        float wB2 = (jB2 < len) ? rowsum[sB0.z] : 0.0f;
        float wB3 = (jB3 < len) ? rowsum[sB0.w] : 0.0f;
        float wB4 = (jB4 < len) ? rowsum[sB1.x] : 0.0f;
        float wB5 = (jB5 < len) ? rowsum[sB1.y] : 0.0f;
        float wB6 = (jB6 < len) ? rowsum[sB1.z] : 0.0f;
        float wB7 = (jB7 < len) ? rowsum[sB1.w] : 0.0f;

        // (3) commit stage k (gathers arrived one iter ago)
        if (jA0 < len) atomicAdd(&lds[jA0], wA0);
        if (jA1 < len) atomicAdd(&lds[jA1], wA1);
        if (jA2 < len) atomicAdd(&lds[jA2], wA2);
        if (jA3 < len) atomicAdd(&lds[jA3], wA3);
        if (jA4 < len) atomicAdd(&lds[jA4], wA4);
        if (jA5 < len) atomicAdd(&lds[jA5], wA5);
        if (jA6 < len) atomicAdd(&lds[jA6], wA6);
        if (jA7 < len) atomicAdd(&lds[jA7], wA7);

        // rotate stages
        eA = eB; eB = eC;
        dB0 = dC0; dB1 = dC1; sB0 = sC0; sB1 = sC1;
        jA0 = jB0; jA1 = jB1; jA2 = jB2; jA3 = jB3;
        jA4 = jB4; jA5 = jB5; jA6 = jB6; jA7 = jB7;
        wA0 = wB0; wA1 = wB1; wA2 = wB2; wA3 = wB3;
        wA4 = wB4; wA5 = wB5; wA6 = wB6; wA7 = wB7;
    }
    __syncthreads();

    // flush LDS slice as bf16 (halves flush + reduce traffic)
    unsigned short* __restrict__ dstp = copies + ((size_t)s * B + b) * SLICE;
    const int len4 = (int)len >> 2;
    for (int i = tid; i < len4; i += TPB) {
        const float4 v = reinterpret_cast<const float4*>(lds)[i];
        ushort4 o;
        o.x = f2bf(v.x); o.y = f2bf(v.y); o.z = f2bf(v.z); o.w = f2bf(v.w);
        reinterpret_cast<ushort4*>(dstp)[i] = o;
    }
}

// ---------------------------------------------------------------------------
// Kernel 3: reduce the B bf16 copies per slice + activation chain + int cast.
// ---------------------------------------------------------------------------
__global__ void __launch_bounds__(256) reduce_final_kernel(
    const unsigned short* __restrict__ copies,
    int B,
    int* __restrict__ out)
{
    const int i4 = (int)(blockIdx.x * blockDim.x + threadIdx.x);
    if (i4 >= N_NODES / 4) return;

    const int s  = (i4 >= 2 * SLICE4) ? 2 : (i4 >= SLICE4 ? 1 : 0);
    const int j4 = i4 - s * SLICE4;

    float ax = 0.0f, ay = 0.0f, az = 0.0f, aw = 0.0f;
    const ushort4* base = reinterpret_cast<const ushort4*>(copies)
                        + (size_t)s * B * SLICE4 + j4;
    #pragma unroll 4
    for (int c = 0; c < B; ++c) {
        const ushort4 v = base[(size_t)c * SLICE4];
        ax += bf2f(v.x); ay += bf2f(v.y); az += bf2f(v.z); aw += bf2f(v.w);
    }

    auto act = [](float x) -> int {
        const float a1 = (x  > 0.0f) ? x  : 0.1f * x;
        const float r2 = 16.0f * a1;
        const float a2 = (r2 > 0.0f) ? r2 : 0.1f * r2;
        return (int)(10.0f * a2);
    };

    int4 o;
    o.x = act(ax); o.y = act(ay); o.z = act(az); o.w = act(aw);
    reinterpret_cast<int4*>(out)[i4] = o;
}

extern "C" void kernel_launch(void* const* d_in, const int* in_sizes, int n_in,
                              void* d_out, int out_size, void* d_ws, size_t ws_size,
                              hipStream_t stream)
{
    const float* feat     = (const float*)d_in[0];
    const int*   edge_src = (const int*)d_in[1];
    const int*   edge_dst = (const int*)d_in[2];
    int*         out      = (int*)d_out;

    float* rowsum = (float*)d_ws;                                  // N_NODES f32
    unsigned short* copies = (unsigned short*)(rowsum + N_NODES);  // 3*B*SLICE bf16

    size_t avail = (ws_size > (size_t)N_NODES * 4) ? ws_size - (size_t)N_NODES * 4 : 0;
    int B = (int)(avail / ((size_t)N_SLICES * SLICE * 2));
    if (B > MAX_B) B = MAX_B;
    if (B < 1) B = 1;

    int epb = (N_EDGES + B - 1) / B;
    epb = (epb + 7) & ~7;

    // Kernel 1: 32 threads per node
    {
        const int threads = 256;
        const long long total = (long long)N_NODES * 32;
        const int blocks = (int)((total + threads - 1) / threads);
        rowsum_kernel<<<blocks, threads, 0, stream>>>(feat, rowsum);
    }

    // Kernel 2: grid (B, 3) — LDS-privatized pipelined scatter
    {
        dim3 grid(B, N_SLICES);
        scatter_kernel<<<grid, TPB, 0, stream>>>(edge_src, edge_dst, rowsum,
                                                 copies, B, epb);
    }

    // Kernel 3: fused reduce + activations + int cast
    {
        const int threads = 256;
        const int blocks = (N_NODES / 4 + threads - 1) / threads;
        reduce_final_kernel<<<blocks, threads, 0, stream>>>(copies, B, out);
    }
}

// Round 6
// 50.930 us; speedup vs baseline: 1.0441x; 1.0441x over previous
//
#include <hip/hip_runtime.h>

#define N_NODES  100000
#define N_EDGES  3200000
#define D_FEAT   128
#define SLICE    33344         // 3 slices cover 100000; 130.25 KiB LDS
#define SLICE4   (SLICE / 4)
#define N_SLICES 3
#define NCHUNK   80            // edge chunks; grid = 240 = 10 groups of 24
#define EPB      40000         // N_EDGES / NCHUNK, multiple of 8
#define EPT      8             // edges per thread per pipeline stage
#define TPB      1024
#define STRIDE   (TPB * EPT)   // 8192 edges per stage per block

__device__ __forceinline__ unsigned short f2bf(float f) {
    union { float f; unsigned u; } c; c.f = f;
    unsigned r = c.u + 0x7FFFu + ((c.u >> 16) & 1u);   // round-nearest-even
    return (unsigned short)(r >> 16);
}
__device__ __forceinline__ float bf2f(unsigned short h) {
    union { unsigned u; float f; } c; c.u = ((unsigned)h) << 16; return c.f;
}

// ---------------------------------------------------------------------------
// Kernel 1: per-node feature row-sum. 32 lanes per row, float4 per lane.
// ---------------------------------------------------------------------------
__global__ void __launch_bounds__(256) rowsum_kernel(
    const float* __restrict__ feat,
    float* __restrict__ rowsum)
{
    const int gid = (int)(blockIdx.x * blockDim.x + threadIdx.x);
    const int row = gid >> 5;
    const int sub = gid & 31;
    if (row >= N_NODES) return;

    const float4 v = reinterpret_cast<const float4*>(
        feat + (size_t)row * D_FEAT)[sub];
    float s = (v.x + v.y) + (v.z + v.w);

    #pragma unroll
    for (int off = 16; off > 0; off >>= 1)
        s += __shfl_xor(s, off, 64);

    if (sub == 0) rowsum[row] = s;
}

// ---------------------------------------------------------------------------
// Kernel 2: LDS-privatized scatter, 3-stage pipeline, XCD-sibling swizzle.
// bid = g*24 + tier*8 + xcd ; slice = tier ; chunk = g*8 + xcd.
// The 3 blocks sharing a chunk have IDs differing by 8 -> same XCD
// (round-robin dispatch) -> chunk streams from HBM once, L2-hits twice.
// ---------------------------------------------------------------------------
__global__ void __launch_bounds__(TPB) scatter_kernel(
    const int* __restrict__ edge_src,
    const int* __restrict__ edge_dst,
    const float* __restrict__ rowsum,
    unsigned short* __restrict__ copies)
{
    __shared__ float lds[SLICE];

    const int tid  = (int)threadIdx.x;
    const int bid  = (int)blockIdx.x;
    const int g    = bid / 24;
    const int r    = bid % 24;
    const int xcd  = r & 7;
    const int s    = r >> 3;              // slice (tier)
    const int b    = g * 8 + xcd;         // chunk
    const int lo   = s * SLICE;
    const unsigned len = (unsigned)((N_NODES - lo < SLICE) ? (N_NODES - lo) : SLICE);

    float4 z; z.x = z.y = z.z = z.w = 0.0f;
    for (int i = tid; i < SLICE4; i += TPB)
        reinterpret_cast<float4*>(lds)[i] = z;
    __syncthreads();

    const int begin = b * EPB;
    const int end   = (begin + EPB < N_EDGES) ? begin + EPB : N_EDGES;

    int eA = begin + tid * EPT;   // stage being committed
    int eB = eA + STRIDE;         // stage being gathered

    int4 dA0, dA1, sA0, sA1, dB0, dB1, sB0, sB1;
    if (eA     < end) { dA0 = *(const int4*)(edge_dst + eA);     sA0 = *(const int4*)(edge_src + eA); }
    if (eA + 4 < end) { dA1 = *(const int4*)(edge_dst + eA + 4); sA1 = *(const int4*)(edge_src + eA + 4); }
    if (eB     < end) { dB0 = *(const int4*)(edge_dst + eB);     sB0 = *(const int4*)(edge_src + eB); }
    if (eB + 4 < end) { dB1 = *(const int4*)(edge_dst + eB + 4); sB1 = *(const int4*)(edge_src + eB + 4); }

    unsigned jA0, jA1, jA2, jA3, jA4, jA5, jA6, jA7;
    float    wA0, wA1, wA2, wA3, wA4, wA5, wA6, wA7;
    {
        const bool v0 = (eA < end), v1 = (eA + 4 < end);
        jA0 = v0 ? (unsigned)(dA0.x - lo) : 0xFFFFFFFFu;
        jA1 = v0 ? (unsigned)(dA0.y - lo) : 0xFFFFFFFFu;
        jA2 = v0 ? (unsigned)(dA0.z - lo) : 0xFFFFFFFFu;
        jA3 = v0 ? (unsigned)(dA0.w - lo) : 0xFFFFFFFFu;
        jA4 = v1 ? (unsigned)(dA1.x - lo) : 0xFFFFFFFFu;
        jA5 = v1 ? (unsigned)(dA1.y - lo) : 0xFFFFFFFFu;
        jA6 = v1 ? (unsigned)(dA1.z - lo) : 0xFFFFFFFFu;
        jA7 = v1 ? (unsigned)(dA1.w - lo) : 0xFFFFFFFFu;
        wA0 = (jA0 < len) ? rowsum[sA0.x] : 0.0f;
        wA1 = (jA1 < len) ? rowsum[sA0.y] : 0.0f;
        wA2 = (jA2 < len) ? rowsum[sA0.z] : 0.0f;
        wA3 = (jA3 < len) ? rowsum[sA0.w] : 0.0f;
        wA4 = (jA4 < len) ? rowsum[sA1.x] : 0.0f;
        wA5 = (jA5 < len) ? rowsum[sA1.y] : 0.0f;
        wA6 = (jA6 < len) ? rowsum[sA1.z] : 0.0f;
        wA7 = (jA7 < len) ? rowsum[sA1.w] : 0.0f;
    }

    while (eA < end) {
        const int eC = eB + STRIDE;
        int4 dC0, dC1, sC0, sC1;
        if (eC     < end) { dC0 = *(const int4*)(edge_dst + eC);     sC0 = *(const int4*)(edge_src + eC); }
        if (eC + 4 < end) { dC1 = *(const int4*)(edge_dst + eC + 4); sC1 = *(const int4*)(edge_src + eC + 4); }

        const bool v0 = (eB < end), v1 = (eB + 4 < end);
        unsigned jB0 = v0 ? (unsigned)(dB0.x - lo) : 0xFFFFFFFFu;
        unsigned jB1 = v0 ? (unsigned)(dB0.y - lo) : 0xFFFFFFFFu;
        unsigned jB2 = v0 ? (unsigned)(dB0.z - lo) : 0xFFFFFFFFu;
        unsigned jB3 = v0 ? (unsigned)(dB0.w - lo) : 0xFFFFFFFFu;
        unsigned jB4 = v1 ? (unsigned)(dB1.x - lo) : 0xFFFFFFFFu;
        unsigned jB5 = v1 ? (unsigned)(dB1.y - lo) : 0xFFFFFFFFu;
        unsigned jB6 = v1 ? (unsigned)(dB1.z - lo) : 0xFFFFFFFFu;
        unsigned jB7 = v1 ? (unsigned)(dB1.w - lo) : 0xFFFFFFFFu;
        float wB0 = (jB0 < len) ? rowsum[sB0.x] : 0.0f;
        float wB1 = (jB1 < len) ? rowsum[sB0.y] : 0.0f;
        float wB2 = (jB2 < len) ? rowsum[sB0.z] : 0.0f;
        float wB3 = (jB3 < len) ? rowsum[sB0.w] : 0.0f;
        float wB4 = (jB4 < len) ? rowsum[sB1.x] : 0.0f;
        float wB5 = (jB5 < len) ? rowsum[sB1.y] : 0.0f;
        float wB6 = (jB6 < len) ? rowsum[sB1.z] : 0.0f;
        float wB7 = (jB7 < len) ? rowsum[sB1.w] : 0.0f;

        if (jA0 < len) atomicAdd(&lds[jA0], wA0);
        if (jA1 < len) atomicAdd(&lds[jA1], wA1);
        if (jA2 < len) atomicAdd(&lds[jA2], wA2);
        if (jA3 < len) atomicAdd(&lds[jA3], wA3);
        if (jA4 < len) atomicAdd(&lds[jA4], wA4);
        if (jA5 < len) atomicAdd(&lds[jA5], wA5);
        if (jA6 < len) atomicAdd(&lds[jA6], wA6);
        if (jA7 < len) atomicAdd(&lds[jA7], wA7);

        eA = eB; eB = eC;
        dB0 = dC0; dB1 = dC1; sB0 = sC0; sB1 = sC1;
        jA0 = jB0; jA1 = jB1; jA2 = jB2; jA3 = jB3;
        jA4 = jB4; jA5 = jB5; jA6 = jB6; jA7 = jB7;
        wA0 = wB0; wA1 = wB1; wA2 = wB2; wA3 = wB3;
        wA4 = wB4; wA5 = wB5; wA6 = wB6; wA7 = wB7;
    }
    __syncthreads();

    // flush LDS slice as bf16 partials
    unsigned short* __restrict__ dstp = copies + ((size_t)s * NCHUNK + b) * SLICE;
    const int len4 = (int)len >> 2;
    for (int i = tid; i < len4; i += TPB) {
        const float4 v = reinterpret_cast<const float4*>(lds)[i];
        ushort4 o;
        o.x = f2bf(v.x); o.y = f2bf(v.y); o.z = f2bf(v.z); o.w = f2bf(v.w);
        reinterpret_cast<ushort4*>(dstp)[i] = o;
    }
}

// ---------------------------------------------------------------------------
// Kernel 3: reduce the NCHUNK bf16 copies per slice + activations + int cast.
// ---------------------------------------------------------------------------
__global__ void __launch_bounds__(256) reduce_final_kernel(
    const unsigned short* __restrict__ copies,
    int* __restrict__ out)
{
    const int i4 = (int)(blockIdx.x * blockDim.x + threadIdx.x);
    if (i4 >= N_NODES / 4) return;

    const int s  = (i4 >= 2 * SLICE4) ? 2 : (i4 >= SLICE4 ? 1 : 0);
    const int j4 = i4 - s * SLICE4;

    float ax = 0.0f, ay = 0.0f, az = 0.0f, aw = 0.0f;
    const ushort4* base = reinterpret_cast<const ushort4*>(copies)
                        + (size_t)s * NCHUNK * SLICE4 + j4;
    #pragma unroll 4
    for (int c = 0; c < NCHUNK; ++c) {
        const ushort4 v = base[(size_t)c * SLICE4];
        ax += bf2f(v.x); ay += bf2f(v.y); az += bf2f(v.z); aw += bf2f(v.w);
    }

    auto act = [](float x) -> int {
        const float a1 = (x  > 0.0f) ? x  : 0.1f * x;
        const float r2 = 16.0f * a1;
        const float a2 = (r2 > 0.0f) ? r2 : 0.1f * r2;
        return (int)(10.0f * a2);
    };

    int4 o;
    o.x = act(ax); o.y = act(ay); o.z = act(az); o.w = act(aw);
    reinterpret_cast<int4*>(out)[i4] = o;
}

extern "C" void kernel_launch(void* const* d_in, const int* in_sizes, int n_in,
                              void* d_out, int out_size, void* d_ws, size_t ws_size,
                              hipStream_t stream)
{
    const float* feat     = (const float*)d_in[0];
    const int*   edge_src = (const int*)d_in[1];
    const int*   edge_dst = (const int*)d_in[2];
    int*         out      = (int*)d_out;

    float* rowsum = (float*)d_ws;                                  // N_NODES f32
    unsigned short* copies = (unsigned short*)(rowsum + N_NODES);  // 3*NCHUNK*SLICE bf16 (~16 MB)

    // Kernel 1: 32 threads per node
    {
        const int threads = 256;
        const long long total = (long long)N_NODES * 32;
        const int blocks = (int)((total + threads - 1) / threads);
        rowsum_kernel<<<blocks, threads, 0, stream>>>(feat, rowsum);
    }

    // Kernel 2: 240 blocks, XCD-sibling swizzled (slice siblings share L2)
    scatter_kernel<<<N_SLICES * NCHUNK, TPB, 0, stream>>>(edge_src, edge_dst,
                                                          rowsum, copies);

    // Kernel 3: fused reduce + activations + int cast
    {
        const int threads = 256;
        const int blocks = (N_NODES / 4 + threads - 1) / threads;
        reduce_final_kernel<<<blocks, threads, 0, stream>>>(copies, out);
    }
}